// Round 1
// baseline (148.184 us; speedup 1.0000x reference)
//
#include <hip/hip_runtime.h>

// Tile geometry: 32x32 output tile per block.
// img_p (padded img + noise) needed at radius 3  -> 38x38 per channel
// img_r needed at radius 2                        -> 36x36
// img_3d_mod needed at radius 1                   -> 34x34
#define TS 32
#define PW 38
#define PS 39   // LDS row stride (pad +1)
#define RW 36
#define RS 37
#define MW 34
#define MS 35

__global__ __launch_bounds__(256)
void gdfn_kernel(const float* __restrict__ img,
                 const float* __restrict__ noise,
                 const float* __restrict__ re_mask,
                 const int*   __restrict__ sel,
                 const int*   __restrict__ mix_sel,
                 float*       __restrict__ out)
{
    constexpr int H = 512, W = 512, C = 3, HP = 514, WP = 514;
    const int b   = blockIdx.z;
    const int h0  = blockIdx.y * TS;
    const int w0  = blockIdx.x * TS;
    const int tid = threadIdx.x;

    const size_t imgB = (size_t)b * C * H * W;
    const size_t noiB = (size_t)b * C * HP * WP;

    // ---- load output-tile img values (needed for every exit path) ----
    float vimg[3][4];
#pragma unroll
    for (int it = 0; it < 4; ++it) {
        int idx = tid + it * 256;
        int ty = idx >> 5, tx = idx & 31;
        size_t off = (size_t)(h0 + ty) * W + (w0 + tx);
#pragma unroll
        for (int c = 0; c < 3; ++c)
            vimg[c][it] = img[imgB + (size_t)c * H * W + off];
    }

    // ---- fast path 1: batch not selected -> out = img ----
    if (!sel[b]) {
#pragma unroll
        for (int it = 0; it < 4; ++it) {
            int idx = tid + it * 256;
            int ty = idx >> 5, tx = idx & 31;
            size_t off = (size_t)(h0 + ty) * W + (w0 + tx);
#pragma unroll
            for (int c = 0; c < 3; ++c)
                out[imgB + (size_t)c * H * W + off] = vimg[c][it];
        }
        return;
    }

    // ---- load re_mask tile; fast path 2: all ones -> out = img ----
    float vrm[3][4];
    int allone = 1;
#pragma unroll
    for (int it = 0; it < 4; ++it) {
        int idx = tid + it * 256;
        int ty = idx >> 5, tx = idx & 31;
        size_t off = (size_t)(h0 + ty) * W + (w0 + tx);
#pragma unroll
        for (int c = 0; c < 3; ++c) {
            float r = re_mask[imgB + (size_t)c * H * W + off];
            vrm[c][it] = r;
            allone &= (r == 1.0f);
        }
    }
    allone = __syncthreads_and(allone);
    if (allone) {
#pragma unroll
        for (int it = 0; it < 4; ++it) {
            int idx = tid + it * 256;
            int ty = idx >> 5, tx = idx & 31;
            size_t off = (size_t)(h0 + ty) * W + (w0 + tx);
#pragma unroll
            for (int c = 0; c < 3; ++c)
                out[imgB + (size_t)c * H * W + off] = vimg[c][it];
        }
        return;
    }

    // ---- heavy path ----
    __shared__ float s_imgp[3 * PW * PS];  // padded img + noise, radius 3
    __shared__ float s_imgr[RW * RS];      // weighted local mean, radius 2
    __shared__ float s_mod [MW * MS];      // selected weight, radius 1

    // Stage 0: img_p = pad(img,1) + noise, region rows/cols [h0-2, h0+35] in padded coords
    for (int idx = tid; idx < 3 * PW * PW; idx += 256) {
        int c  = idx / (PW * PW);
        int r  = idx - c * (PW * PW);
        int ly = r / PW, lx = r - ly * PW;
        int py = h0 - 2 + ly, px = w0 - 2 + lx;   // padded-image coords
        float v = 0.f;
        if (py >= 0 && py < HP && px >= 0 && px < WP) {
            v = noise[noiB + (size_t)c * HP * WP + (size_t)py * WP + px];
            int iy = py - 1, ix = px - 1;
            if (iy >= 0 && iy < H && ix >= 0 && ix < W)
                v += img[imgB + (size_t)c * H * W + (size_t)iy * W + ix];
        }
        s_imgp[c * PW * PS + ly * PS + lx] = v;
    }
    __syncthreads();

    // Stage 1: img_r over tile+2 halo.
    // w = exp(-(x-mean)^2/(2*std^2)), std^2(ddof=1) = ssd/8  =>  exp(-4 d^2/ssd)
    for (int idx = tid; idx < RW * RW; idx += 256) {
        int sy = idx / RW, sx = idx - sy * RW;
        int ry = h0 - 2 + sy, rx = w0 - 2 + sx;
        if (ry < 0 || ry >= H || rx < 0 || rx >= W) continue;
        float v[3][9], w3[9];
#pragma unroll
        for (int c = 0; c < 3; ++c) {
            const float* sp = &s_imgp[c * PW * PS + sy * PS + sx];
            float sum = 0.f;
#pragma unroll
            for (int i = 0; i < 3; ++i)
#pragma unroll
                for (int j = 0; j < 3; ++j) {
                    float x = sp[i * PS + j];
                    v[c][i * 3 + j] = x;
                    sum += x;
                }
            float mean = sum * (1.f / 9.f);
            float ssd = 0.f;
#pragma unroll
            for (int k = 0; k < 9; ++k) { float d = v[c][k] - mean; ssd += d * d; }
            float inv = -4.f / ssd;
#pragma unroll
            for (int k = 0; k < 9; ++k) {
                float d  = v[c][k] - mean;
                float wv = expf(d * d * inv);
                w3[k] = (c == 0) ? wv : fminf(w3[k], wv);
            }
        }
        float num = 0.f, den = 0.f;
#pragma unroll
        for (int k = 0; k < 9; ++k) {
            den += w3[k];
            num += (v[0][k] + v[1][k] + v[2][k]) * w3[k];
        }
        s_imgr[sy * RS + sx] = num / den;
    }
    __syncthreads();

    const int msel = mix_sel[b];

    // Stage 2: first-occurrence argmin/argmax over img_r 3x3 (OOB = 0.0 exactly),
    // then recompute the selected weight img_3d[q][k_sel].
    for (int idx = tid; idx < MW * MW; idx += 256) {
        int my = idx / MW, mx = idx - my * MW;
        int qy = h0 - 1 + my, qx = w0 - 1 + mx;
        if (qy < 0 || qy >= H || qx < 0 || qx >= W) continue;
        float bmin = 0.f, bmax = 0.f;
        int imin = 0, imax = 0;
#pragma unroll
        for (int k = 0; k < 9; ++k) {
            int di = k / 3 - 1, dj = k % 3 - 1;
            int ny = qy + di, nx = qx + dj;
            float val = 0.f;
            if (ny >= 0 && ny < H && nx >= 0 && nx < W)
                val = s_imgr[(my + 1 + di) * RS + (mx + 1 + dj)];
            if (k == 0) { bmin = val; bmax = val; }
            else {
                if (val < bmin) { bmin = val; imin = k; }
                if (val > bmax) { bmax = val; imax = k; }
            }
        }
        int ks = msel ? imax : imin;
        int si = ks / 3, sj = ks % 3;
        float wmin = 1e30f;
#pragma unroll
        for (int c = 0; c < 3; ++c) {
            const float* sp = &s_imgp[c * PW * PS + (my + 1) * PS + (mx + 1)];
            float vv[9];
            float sum = 0.f;
#pragma unroll
            for (int i = 0; i < 3; ++i)
#pragma unroll
                for (int j = 0; j < 3; ++j) {
                    float x = sp[i * PS + j];
                    vv[i * 3 + j] = x;
                    sum += x;
                }
            float mean = sum * (1.f / 9.f);
            float ssd = 0.f;
#pragma unroll
            for (int k = 0; k < 9; ++k) { float d = vv[k] - mean; ssd += d * d; }
            float d  = vv[si * 3 + sj] - mean;
            float wv = expf(d * d * (-4.f / ssd));
            wmin = fminf(wmin, wv);
        }
        s_mod[my * MS + mx] = wmin;
    }
    __syncthreads();

    // Stage 3: img_mod = sum(img_e * m_e)/sum(m_e) per channel, then blend.
#pragma unroll
    for (int it = 0; it < 4; ++it) {
        int idx = tid + it * 256;
        int ty = idx >> 5, tx = idx & 31;
        int gy = h0 + ty, gx = w0 + tx;
        float m[9];
        float mden = 0.f;
#pragma unroll
        for (int k = 0; k < 9; ++k) {
            int di = k / 3 - 1, dj = k % 3 - 1;
            int ny = gy + di, nx = gx + dj;
            float mv = 0.f;
            if (ny >= 0 && ny < H && nx >= 0 && nx < W)
                mv = s_mod[(ty + di + 1) * MS + (tx + dj + 1)];
            m[k] = mv;
            mden += mv;
        }
#pragma unroll
        for (int c = 0; c < 3; ++c) {
            const float* sp = &s_imgp[c * PW * PS + (ty + 2) * PS + (tx + 2)];
            float numc = 0.f;
#pragma unroll
            for (int i = 0; i < 3; ++i)
#pragma unroll
                for (int j = 0; j < 3; ++j)
                    numc += sp[i * PS + j] * m[i * 3 + j];
            float imod = numc / mden;
            float rm   = vrm[c][it];
            float o    = imod * (1.f - rm) + vimg[c][it] * rm;
            out[imgB + (size_t)c * H * W + (size_t)gy * W + gx] = o;
        }
    }
}

extern "C" void kernel_launch(void* const* d_in, const int* in_sizes, int n_in,
                              void* d_out, int out_size, void* d_ws, size_t ws_size,
                              hipStream_t stream)
{
    const float* img     = (const float*)d_in[0];
    const float* noise   = (const float*)d_in[1];
    const float* re_mask = (const float*)d_in[2];
    const int*   sel     = (const int*)d_in[3];
    const int*   mix_sel = (const int*)d_in[4];
    float*       out     = (float*)d_out;

    const int B = in_sizes[3];          // 8
    dim3 grid(512 / TS, 512 / TS, B);   // 16 x 16 x 8
    dim3 block(256);
    hipLaunchKernelGGL(gdfn_kernel, grid, block, 0, stream,
                       img, noise, re_mask, sel, mix_sel, out);
}

// Round 2
// 147.798 us; speedup vs baseline: 1.0026x; 1.0026x over previous
//
#include <hip/hip_runtime.h>

// Tile geometry: 32x32 output tile per block. Thread t handles row t>>3,
// cols ((t&7)*4 .. +3) -> all global I/O is float4 (aligned: W=512, tx4%32==0... tx4%4==0, byte offset %16==0).
// img_p (padded img + noise) needed at radius 3  -> 38x38 per channel
// img_r needed at radius 2                        -> 36x36
// img_3d_mod needed at radius 1                   -> 34x34
#define TS 32
#define PW 38
#define PS 39   // LDS row stride (pad +1)
#define RW 36
#define RS 37
#define MW 34
#define MS 35

__global__ __launch_bounds__(256)
void gdfn_kernel(const float* __restrict__ img,
                 const float* __restrict__ noise,
                 const float* __restrict__ re_mask,
                 const int*   __restrict__ sel,
                 const int*   __restrict__ mix_sel,
                 float*       __restrict__ out)
{
    constexpr int H = 512, W = 512, C = 3, HP = 514, WP = 514;
    const int b   = blockIdx.z;
    const int h0  = blockIdx.y * TS;
    const int w0  = blockIdx.x * TS;
    const int tid = threadIdx.x;
    const int ty  = tid >> 3;          // 0..31
    const int tx4 = (tid & 7) << 2;    // 0,4,...,28

    const size_t HWs  = (size_t)H * W;
    const size_t imgB = (size_t)b * C * HWs;
    const size_t noiB = (size_t)b * C * HP * WP;
    const size_t po   = (size_t)(h0 + ty) * W + (w0 + tx4);

    // ---- fast path 1: batch not selected -> out = img (vector copy, no barrier) ----
    if (!sel[b]) {
#pragma unroll
        for (int c = 0; c < 3; ++c) {
            const float4 v = *(const float4*)(img + imgB + c * HWs + po);
            *(float4*)(out + imgB + c * HWs + po) = v;
        }
        return;
    }

    // ---- load img + re_mask tiles as float4; fast path 2: mask all ones ----
    float4 vimg4[3], vrm4[3];
    int allone = 1;
#pragma unroll
    for (int c = 0; c < 3; ++c) {
        vimg4[c] = *(const float4*)(img + imgB + c * HWs + po);
        float4 r = *(const float4*)(re_mask + imgB + c * HWs + po);
        vrm4[c] = r;
        allone &= (r.x == 1.0f) & (r.y == 1.0f) & (r.z == 1.0f) & (r.w == 1.0f);
    }
    allone = __syncthreads_and(allone);
    if (allone) {
#pragma unroll
        for (int c = 0; c < 3; ++c)
            *(float4*)(out + imgB + c * HWs + po) = vimg4[c];
        return;
    }

    // ---- heavy path (only tiles overlapping the erase rectangle, ~196 blocks) ----
    __shared__ float s_imgp[3 * PW * PS];  // padded img + noise, radius 3
    __shared__ float s_imgr[RW * RS];      // weighted local mean, radius 2
    __shared__ float s_mod [MW * MS];      // selected weight, radius 1

    // Stage 0: img_p = pad(img,1) + noise over padded rows/cols [h0-2, h0+35].
    // Fully unrolled so all 17 iterations' global loads are in flight at once.
#pragma unroll
    for (int it = 0; it < 17; ++it) {
        int idx = tid + it * 256;
        if (idx < 3 * PW * PW) {
            int c  = idx / (PW * PW);
            int r  = idx - c * (PW * PW);
            int ly = r / PW, lx = r - ly * PW;
            int py = h0 - 2 + ly, px = w0 - 2 + lx;   // padded-image coords
            float v = 0.f;
            if (py >= 0 && py < HP && px >= 0 && px < WP) {
                v = noise[noiB + (size_t)c * HP * WP + (size_t)py * WP + px];
                int iy = py - 1, ix = px - 1;
                if (iy >= 0 && iy < H && ix >= 0 && ix < W)
                    v += img[imgB + (size_t)c * HWs + (size_t)iy * W + ix];
            }
            s_imgp[c * PW * PS + ly * PS + lx] = v;
        }
    }
    __syncthreads();

    // Stage 1: img_r over tile+2 halo.
    // w = exp(-(x-mean)^2/(2*std^2)), std^2(ddof=1) = ssd/8  =>  exp(-4 d^2/ssd)
    for (int idx = tid; idx < RW * RW; idx += 256) {
        int sy = idx / RW, sx = idx - sy * RW;
        int ry = h0 - 2 + sy, rx = w0 - 2 + sx;
        if (ry < 0 || ry >= H || rx < 0 || rx >= W) continue;
        float v[3][9], w3[9];
#pragma unroll
        for (int c = 0; c < 3; ++c) {
            const float* sp = &s_imgp[c * PW * PS + sy * PS + sx];
            float sum = 0.f;
#pragma unroll
            for (int i = 0; i < 3; ++i)
#pragma unroll
                for (int j = 0; j < 3; ++j) {
                    float x = sp[i * PS + j];
                    v[c][i * 3 + j] = x;
                    sum += x;
                }
            float mean = sum * (1.f / 9.f);
            float ssd = 0.f;
#pragma unroll
            for (int k = 0; k < 9; ++k) { float d = v[c][k] - mean; ssd += d * d; }
            float inv = -4.f / ssd;
#pragma unroll
            for (int k = 0; k < 9; ++k) {
                float d  = v[c][k] - mean;
                float wv = expf(d * d * inv);
                w3[k] = (c == 0) ? wv : fminf(w3[k], wv);
            }
        }
        float num = 0.f, den = 0.f;
#pragma unroll
        for (int k = 0; k < 9; ++k) {
            den += w3[k];
            num += (v[0][k] + v[1][k] + v[2][k]) * w3[k];
        }
        s_imgr[sy * RS + sx] = num / den;
    }
    __syncthreads();

    const int msel = mix_sel[b];

    // Stage 2: first-occurrence argmin/argmax over img_r 3x3 (OOB = 0.0 exactly),
    // then recompute the selected weight img_3d[q][k_sel].
    for (int idx = tid; idx < MW * MW; idx += 256) {
        int my = idx / MW, mx = idx - my * MW;
        int qy = h0 - 1 + my, qx = w0 - 1 + mx;
        if (qy < 0 || qy >= H || qx < 0 || qx >= W) continue;
        float bmin = 0.f, bmax = 0.f;
        int imin = 0, imax = 0;
#pragma unroll
        for (int k = 0; k < 9; ++k) {
            int di = k / 3 - 1, dj = k % 3 - 1;
            int ny = qy + di, nx = qx + dj;
            float val = 0.f;
            if (ny >= 0 && ny < H && nx >= 0 && nx < W)
                val = s_imgr[(my + 1 + di) * RS + (mx + 1 + dj)];
            if (k == 0) { bmin = val; bmax = val; }
            else {
                if (val < bmin) { bmin = val; imin = k; }
                if (val > bmax) { bmax = val; imax = k; }
            }
        }
        int ks = msel ? imax : imin;
        int si = ks / 3, sj = ks % 3;
        float wmin = 1e30f;
#pragma unroll
        for (int c = 0; c < 3; ++c) {
            const float* sp = &s_imgp[c * PW * PS + (my + 1) * PS + (mx + 1)];
            float vv[9];
            float sum = 0.f;
#pragma unroll
            for (int i = 0; i < 3; ++i)
#pragma unroll
                for (int j = 0; j < 3; ++j) {
                    float x = sp[i * PS + j];
                    vv[i * 3 + j] = x;
                    sum += x;
                }
            float mean = sum * (1.f / 9.f);
            float ssd = 0.f;
#pragma unroll
            for (int k = 0; k < 9; ++k) { float d = vv[k] - mean; ssd += d * d; }
            float d  = vv[si * 3 + sj] - mean;
            float wv = expf(d * d * (-4.f / ssd));
            wmin = fminf(wmin, wv);
        }
        s_mod[my * MS + mx] = wmin;
    }
    __syncthreads();

    // Stage 3: img_mod = sum(img_e * m_e)/sum(m_e) per channel, then blend.
    // Thread handles 4 consecutive pixels (row ty, cols tx4..tx4+3); float4 stores.
    float ovals[3][4];
    const float* vi[3] = { (const float*)&vimg4[0], (const float*)&vimg4[1], (const float*)&vimg4[2] };
    const float* vr[3] = { (const float*)&vrm4[0],  (const float*)&vrm4[1],  (const float*)&vrm4[2]  };
#pragma unroll
    for (int p = 0; p < 4; ++p) {
        int tx = tx4 + p;
        int gy = h0 + ty, gx = w0 + tx;
        float m[9];
        float mden = 0.f;
#pragma unroll
        for (int k = 0; k < 9; ++k) {
            int di = k / 3 - 1, dj = k % 3 - 1;
            int ny = gy + di, nx = gx + dj;
            float mv = 0.f;
            if (ny >= 0 && ny < H && nx >= 0 && nx < W)
                mv = s_mod[(ty + di + 1) * MS + (tx + dj + 1)];
            m[k] = mv;
            mden += mv;
        }
#pragma unroll
        for (int c = 0; c < 3; ++c) {
            const float* sp = &s_imgp[c * PW * PS + (ty + 2) * PS + (tx + 2)];
            float numc = 0.f;
#pragma unroll
            for (int i = 0; i < 3; ++i)
#pragma unroll
                for (int j = 0; j < 3; ++j)
                    numc += sp[i * PS + j] * m[i * 3 + j];
            float imod = numc / mden;
            float rm   = vr[c][p];
            ovals[c][p] = imod * (1.f - rm) + vi[c][p] * rm;
        }
    }
#pragma unroll
    for (int c = 0; c < 3; ++c) {
        float4 o = make_float4(ovals[c][0], ovals[c][1], ovals[c][2], ovals[c][3]);
        *(float4*)(out + imgB + c * HWs + po) = o;
    }
}

extern "C" void kernel_launch(void* const* d_in, const int* in_sizes, int n_in,
                              void* d_out, int out_size, void* d_ws, size_t ws_size,
                              hipStream_t stream)
{
    const float* img     = (const float*)d_in[0];
    const float* noise   = (const float*)d_in[1];
    const float* re_mask = (const float*)d_in[2];
    const int*   sel     = (const int*)d_in[3];
    const int*   mix_sel = (const int*)d_in[4];
    float*       out     = (float*)d_out;

    const int B = in_sizes[3];          // 8
    dim3 grid(512 / TS, 512 / TS, B);   // 16 x 16 x 8
    dim3 block(256);
    hipLaunchKernelGGL(gdfn_kernel, grid, block, 0, stream,
                       img, noise, re_mask, sel, mix_sel, out);
}

// Round 3
// 132.088 us; speedup vs baseline: 1.1219x; 1.1189x over previous
//
#include <hip/hip_runtime.h>

// 32x32 output tile per block, 1024 threads (16 waves = 4/SIMD for latency hiding
// in the heavy path; 256-thread blocks gave 1 wave/SIMD and were stall-bound).
// img_p (padded img + noise) needed at radius 3  -> 38x38 per channel
// img_r needed at radius 2                        -> 36x36
// img_3d_mod needed at radius 1                   -> 34x34
#define TS 32
#define PW 38
#define PS 39   // LDS row stride (pad +1)
#define RW 36
#define RS 37
#define MW 34
#define MS 35

__global__ __launch_bounds__(1024, 4)
void gdfn_kernel(const float* __restrict__ img,
                 const float* __restrict__ noise,
                 const float* __restrict__ re_mask,
                 const int*   __restrict__ sel,
                 const int*   __restrict__ mix_sel,
                 float*       __restrict__ out)
{
    constexpr int H = 512, W = 512, C = 3, HP = 514, WP = 514;
    const int b   = blockIdx.z;
    const int h0  = blockIdx.y * TS;
    const int w0  = blockIdx.x * TS;
    const int tid = threadIdx.x;

    const size_t HWs  = (size_t)H * W;
    const size_t imgB = (size_t)b * C * HWs;
    const size_t noiB = (size_t)b * C * HP * WP;

    // Copy mapping: threads 0..767 each move one float4. c = tid>>8, within-channel
    // r = tid&255 -> row r>>3, cols ((r&7)*4 .. +3). Byte offsets %16 == 0.
    const int cc   = tid >> 8;            // 0..3 (3 inactive)
    const int rr   = tid & 255;
    const int cty  = rr >> 3;
    const int ctx4 = (rr & 7) << 2;
    const size_t cpo = imgB + (size_t)cc * HWs + (size_t)(h0 + cty) * W + (w0 + ctx4);

    // ---- fast path 1: batch not selected -> out = img ----
    if (!sel[b]) {
        if (cc < 3) *(float4*)(out + cpo) = *(const float4*)(img + cpo);
        return;
    }

    // ---- load img + re_mask tiles; fast path 2: mask all ones ----
    float4 vimg4 = make_float4(0.f, 0.f, 0.f, 0.f);
    int allone = 1;
    if (cc < 3) {
        vimg4 = *(const float4*)(img + cpo);
        float4 r = *(const float4*)(re_mask + cpo);
        allone = (r.x == 1.0f) & (r.y == 1.0f) & (r.z == 1.0f) & (r.w == 1.0f);
    }
    allone = __syncthreads_and(allone);
    if (allone) {
        if (cc < 3) *(float4*)(out + cpo) = vimg4;
        return;
    }

    // ---- heavy path (only tiles overlapping the erase rectangle, ~196 blocks) ----
    // Per-pixel mapping for stage 3: 1 pixel/thread.
    const int ty = tid >> 5, tx = tid & 31;
    const int gy = h0 + ty, gx = w0 + tx;
    const size_t p3 = imgB + (size_t)gy * W + gx;

    // Issue stage-3 per-pixel loads NOW so they overlap stages 0-2 (L2-warm).
    float img3[3], rm3[3];
#pragma unroll
    for (int c = 0; c < 3; ++c) {
        img3[c] = img[p3 + c * HWs];
        rm3[c]  = re_mask[p3 + c * HWs];
    }

    __shared__ float s_imgp[3 * PW * PS];  // padded img + noise, radius 3
    __shared__ float s_imgr[RW * RS];      // weighted local mean, radius 2
    __shared__ float s_mod [MW * MS];      // selected weight, radius 1

    // Stage 0: img_p = pad(img,1) + noise over padded rows/cols [h0-2, h0+35].
#pragma unroll
    for (int it = 0; it < 5; ++it) {
        int idx = tid + it * 1024;
        if (idx < 3 * PW * PW) {
            int c  = idx / (PW * PW);
            int r  = idx - c * (PW * PW);
            int ly = r / PW, lx = r - ly * PW;
            int py = h0 - 2 + ly, px = w0 - 2 + lx;   // padded-image coords
            float v = 0.f;
            if (py >= 0 && py < HP && px >= 0 && px < WP) {
                v = noise[noiB + (size_t)c * HP * WP + (size_t)py * WP + px];
                int iy = py - 1, ix = px - 1;
                if (iy >= 0 && iy < H && ix >= 0 && ix < W)
                    v += img[imgB + (size_t)c * HWs + (size_t)iy * W + ix];
            }
            s_imgp[c * PW * PS + ly * PS + lx] = v;
        }
    }
    __syncthreads();

    // Stage 1: img_r over tile+2 halo.
    // w = exp(-(x-mean)^2/(2*std^2)), std^2(ddof=1) = ssd/8  =>  exp(-4 d^2/ssd)
#pragma unroll
    for (int it = 0; it < 2; ++it) {
        int idx = tid + it * 1024;
        if (idx >= RW * RW) continue;
        int sy = idx / RW, sx = idx - sy * RW;
        int ry = h0 - 2 + sy, rx = w0 - 2 + sx;
        if (ry < 0 || ry >= H || rx < 0 || rx >= W) continue;
        float v[3][9], w3[9];
#pragma unroll
        for (int c = 0; c < 3; ++c) {
            const float* sp = &s_imgp[c * PW * PS + sy * PS + sx];
            float sum = 0.f;
#pragma unroll
            for (int i = 0; i < 3; ++i)
#pragma unroll
                for (int j = 0; j < 3; ++j) {
                    float x = sp[i * PS + j];
                    v[c][i * 3 + j] = x;
                    sum += x;
                }
            float mean = sum * (1.f / 9.f);
            float ssd = 0.f;
#pragma unroll
            for (int k = 0; k < 9; ++k) { float d = v[c][k] - mean; ssd += d * d; }
            float inv = -4.f / ssd;
#pragma unroll
            for (int k = 0; k < 9; ++k) {
                float d  = v[c][k] - mean;
                float wv = expf(d * d * inv);
                w3[k] = (c == 0) ? wv : fminf(w3[k], wv);
            }
        }
        float num = 0.f, den = 0.f;
#pragma unroll
        for (int k = 0; k < 9; ++k) {
            den += w3[k];
            num += (v[0][k] + v[1][k] + v[2][k]) * w3[k];
        }
        s_imgr[sy * RS + sx] = num / den;
    }
    __syncthreads();

    const int msel = mix_sel[b];

    // Stage 2: first-occurrence argmin/argmax over img_r 3x3 (OOB = 0.0 exactly),
    // then recompute the selected weight img_3d[q][k_sel].
#pragma unroll
    for (int it = 0; it < 2; ++it) {
        int idx = tid + it * 1024;
        if (idx >= MW * MW) continue;
        int my = idx / MW, mx = idx - my * MW;
        int qy = h0 - 1 + my, qx = w0 - 1 + mx;
        if (qy < 0 || qy >= H || qx < 0 || qx >= W) continue;
        float bmin = 0.f, bmax = 0.f;
        int imin = 0, imax = 0;
#pragma unroll
        for (int k = 0; k < 9; ++k) {
            int di = k / 3 - 1, dj = k % 3 - 1;
            int ny = qy + di, nx = qx + dj;
            float val = 0.f;
            if (ny >= 0 && ny < H && nx >= 0 && nx < W)
                val = s_imgr[(my + 1 + di) * RS + (mx + 1 + dj)];
            if (k == 0) { bmin = val; bmax = val; }
            else {
                if (val < bmin) { bmin = val; imin = k; }
                if (val > bmax) { bmax = val; imax = k; }
            }
        }
        int ks = msel ? imax : imin;
        int si = ks / 3, sj = ks % 3;
        float wmin = 1e30f;
#pragma unroll
        for (int c = 0; c < 3; ++c) {
            const float* sp = &s_imgp[c * PW * PS + (my + 1) * PS + (mx + 1)];
            float vv[9];
            float sum = 0.f;
#pragma unroll
            for (int i = 0; i < 3; ++i)
#pragma unroll
                for (int j = 0; j < 3; ++j) {
                    float x = sp[i * PS + j];
                    vv[i * 3 + j] = x;
                    sum += x;
                }
            float mean = sum * (1.f / 9.f);
            float ssd = 0.f;
#pragma unroll
            for (int k = 0; k < 9; ++k) { float d = vv[k] - mean; ssd += d * d; }
            float d  = vv[si * 3 + sj] - mean;
            float wv = expf(d * d * (-4.f / ssd));
            wmin = fminf(wmin, wv);
        }
        s_mod[my * MS + mx] = wmin;
    }
    __syncthreads();

    // Stage 3: img_mod = sum(img_e * m_e)/sum(m_e) per channel, then blend. 1 px/thread.
    float m[9];
    float mden = 0.f;
#pragma unroll
    for (int k = 0; k < 9; ++k) {
        int di = k / 3 - 1, dj = k % 3 - 1;
        int ny = gy + di, nx = gx + dj;
        float mv = 0.f;
        if (ny >= 0 && ny < H && nx >= 0 && nx < W)
            mv = s_mod[(ty + di + 1) * MS + (tx + dj + 1)];
        m[k] = mv;
        mden += mv;
    }
#pragma unroll
    for (int c = 0; c < 3; ++c) {
        const float* sp = &s_imgp[c * PW * PS + (ty + 2) * PS + (tx + 2)];
        float numc = 0.f;
#pragma unroll
        for (int i = 0; i < 3; ++i)
#pragma unroll
            for (int j = 0; j < 3; ++j)
                numc += sp[i * PS + j] * m[i * 3 + j];
        float imod = numc / mden;
        float rm   = rm3[c];
        out[p3 + c * HWs] = imod * (1.f - rm) + img3[c] * rm;
    }
}

extern "C" void kernel_launch(void* const* d_in, const int* in_sizes, int n_in,
                              void* d_out, int out_size, void* d_ws, size_t ws_size,
                              hipStream_t stream)
{
    const float* img     = (const float*)d_in[0];
    const float* noise   = (const float*)d_in[1];
    const float* re_mask = (const float*)d_in[2];
    const int*   sel     = (const int*)d_in[3];
    const int*   mix_sel = (const int*)d_in[4];
    float*       out     = (float*)d_out;

    const int B = in_sizes[3];          // 8
    dim3 grid(512 / TS, 512 / TS, B);   // 16 x 16 x 8
    dim3 block(1024);
    hipLaunchKernelGGL(gdfn_kernel, grid, block, 0, stream,
                       img, noise, re_mask, sel, mix_sel, out);
}